// Round 2
// baseline (197.143 us; speedup 1.0000x reference)
//
#include <hip/hip_runtime.h>
#include <stdint.h>

typedef unsigned short u16;
typedef short bf16x8 __attribute__((ext_vector_type(8)));
typedef float f32x4 __attribute__((ext_vector_type(4)));

#define S_ 2048
#define HID_ 1024
#define H_ 16
#define D_ 64

#define LOG2E 1.4426950408889634f
#define SCALE_LOG2 0.18033688011112042f   /* 0.125 * log2(e) */
#define MAXC_LOG2 11.541560327111707f     /* 8 * log2(e) */

__device__ __forceinline__ u16 f2bf(float f) {
  uint32_t x = __builtin_bit_cast(uint32_t, f);
  uint32_t r = (x + 0x7fffu + ((x >> 16) & 1u)) >> 16;
  return (u16)r;
}
__device__ __forceinline__ uint32_t packbf2(float a, float b) {
  return (uint32_t)f2bf(a) | ((uint32_t)f2bf(b) << 16);
}
// truncating pack: low16 = bf16(a), high16 = bf16(b), one v_perm_b32
__device__ __forceinline__ uint32_t permpack(float a, float b) {
  return __builtin_amdgcn_perm(__builtin_bit_cast(uint32_t, b),
                               __builtin_bit_cast(uint32_t, a), 0x07060302u);
}

__device__ __forceinline__ void gl2lds16(const void* g, void* l) {
  __builtin_amdgcn_global_load_lds(
      (const __attribute__((address_space(1))) unsigned int*)g,
      (__attribute__((address_space(3))) unsigned int*)l, 16, 0, 0);
}

// ------------- prep: converts + RoPE tables + mask2, one kernel -------------
#define NX_ (1 << 20)
#define NW_ (1 << 18)
#define NROPE_ 65536
__global__ void prep_kernel(const float* __restrict__ X, const float* __restrict__ Wq,
                            const float* __restrict__ Wk, const float* __restrict__ Wv,
                            const float* __restrict__ mask, u16* __restrict__ Xb,
                            u16* __restrict__ Wqb, u16* __restrict__ Wkb,
                            u16* __restrict__ Wvb, float* __restrict__ cos_t,
                            float* __restrict__ sin_t, float* __restrict__ mask2) {
  int i = blockIdx.x * 256 + threadIdx.x;
  if (i < NX_ + 3 * NW_) {
    const float* src;
    u16* dst;
    int off;
    if (i < NX_) {
      src = X; dst = Xb; off = i;
    } else if (i < NX_ + NW_) {
      src = Wq; dst = Wqb; off = i - NX_;
    } else if (i < NX_ + 2 * NW_) {
      src = Wk; dst = Wkb; off = i - NX_ - NW_;
    } else {
      src = Wv; dst = Wvb; off = i - NX_ - 2 * NW_;
    }
    float4 v = ((const float4*)src)[off];
    uint2 packed;
    packed.x = packbf2(v.x, v.y);
    packed.y = packbf2(v.z, v.w);
    ((uint2*)dst)[off] = packed;
  } else if (i < NX_ + 3 * NW_ + NROPE_) {
    int t = i - (NX_ + 3 * NW_);  // 65536 = 2048*32
    int s = t >> 5, j = t & 31;
    float invf = powf(10000.0f, -(float)j * (1.0f / 32.0f));
    float ang = (float)s * invf;
    cos_t[t] = cosf(ang);
    sin_t[t] = sinf(ang);
  } else {
    int t = i - (NX_ + 3 * NW_ + NROPE_);  // 4096 = 2*2048
    mask2[t] = fmaf(mask[t], LOG2E, -MAXC_LOG2);
  }
}

// ---------------- QKV GEMM: single-buffer 32 KB LDS, 2-barrier m97 loop ----------------
// C = X(4096x1024) * W^T. 128x128 tile, BK=64, 4 waves 2x2.
// grid.x in [0,24): which = x>>3 (0:Q 1:K 2:V), nbase = (x&7)*128.
// which<2: SWAPPED mfma operands (C regs run along d) + fused RoPE.
// 32 KB LDS + launch_bounds(256,3) -> all 768 blocks co-resident at 3/CU
// (the 64 KB dbuf version capped at 2/CU: 512 resident + 256-block tail = 1.5 waves).
__global__ __launch_bounds__(256, 3) void qkv_gemm_kernel(
    const u16* __restrict__ X, const u16* __restrict__ Wq, const u16* __restrict__ Wk,
    const u16* __restrict__ Wv, const float* __restrict__ cos_t,
    const float* __restrict__ sin_t, u16* __restrict__ Q, u16* __restrict__ K,
    u16* __restrict__ Vt) {
  __shared__ char smem[32768];  // As @ 0, Bs @ 16K (single buffer)
  int tid = threadIdx.x;
  int lane = tid & 63, wave = tid >> 6;
  int wm = wave >> 1, wn = wave & 1;
  int quad = lane >> 4, l16 = lane & 15;
  int which = blockIdx.x >> 3;
  int nbase = (blockIdx.x & 7) * 128;
  int mbase = blockIdx.y * 128;
  const u16* W = (which == 0) ? Wq : (which == 1) ? Wk : Wv;

  // stage tile 0
#pragma unroll
  for (int it = 0; it < 4; ++it) {
    int i = it * 256 + tid;
    int r = i >> 3, gs = i & 7, gsrc = gs ^ (r & 7);
    gl2lds16(X + (size_t)(mbase + r) * HID_ + gsrc * 8, smem + i * 16);
    gl2lds16(W + (size_t)(nbase + r) * HID_ + gsrc * 8, smem + 16384 + i * 16);
  }

  f32x4 acc[4][4] = {};

  for (int kk = 0; kk < 16; ++kk) {
    __syncthreads();  // staging of tile kk complete (vmcnt drained per-wave + join)
    const char* As = smem;
    const char* Bs = smem + 16384;

#pragma unroll
    for (int kh = 0; kh < 2; ++kh) {
      bf16x8 afrag[4], bfrag[4];
#pragma unroll
      for (int i4 = 0; i4 < 4; ++i4) {
        int r = wm * 64 + i4 * 16 + l16;
        int L = r * 8 + ((kh * 4 + quad) ^ (r & 7));
        afrag[i4] = *(const bf16x8*)(As + L * 16);
      }
#pragma unroll
      for (int j4 = 0; j4 < 4; ++j4) {
        int r = wn * 64 + j4 * 16 + l16;
        int L = r * 8 + ((kh * 4 + quad) ^ (r & 7));
        bfrag[j4] = *(const bf16x8*)(Bs + L * 16);
      }
      if (which == 2) {
#pragma unroll
        for (int i4 = 0; i4 < 4; ++i4)
#pragma unroll
          for (int j4 = 0; j4 < 4; ++j4)
            acc[i4][j4] = __builtin_amdgcn_mfma_f32_16x16x32_bf16(afrag[i4], bfrag[j4],
                                                                  acc[i4][j4], 0, 0, 0);
      } else {
#pragma unroll
        for (int i4 = 0; i4 < 4; ++i4)
#pragma unroll
          for (int j4 = 0; j4 < 4; ++j4)
            acc[i4][j4] = __builtin_amdgcn_mfma_f32_16x16x32_bf16(bfrag[j4], afrag[i4],
                                                                  acc[i4][j4], 0, 0, 0);
      }
    }

    __syncthreads();  // all waves done reading As/Bs
    if (kk < 15) {    // overwrite the single buffer with tile kk+1
      int k0n = (kk + 1) * 64;
#pragma unroll
      for (int it = 0; it < 4; ++it) {
        int i = it * 256 + tid;
        int r = i >> 3, gs = i & 7, gsrc = gs ^ (r & 7);
        gl2lds16(X + (size_t)(mbase + r) * HID_ + k0n + gsrc * 8, smem + i * 16);
        gl2lds16(W + (size_t)(nbase + r) * HID_ + k0n + gsrc * 8, smem + 16384 + i * 16);
      }
    }
  }

  if (which == 2) {
    // C tile: row = m-off = quad*4+reg, col = n-off = l16. 4 regs = 4 consecutive s.
#pragma unroll
    for (int i4 = 0; i4 < 4; ++i4)
#pragma unroll
      for (int j4 = 0; j4 < 4; ++j4) {
        int m = mbase + wm * 64 + i4 * 16 + quad * 4;
        int n = nbase + wn * 64 + j4 * 16 + l16;
        int b = m >> 11, s0 = m & 2047;
        int h = n >> 6, d = n & 63;
        uint2 pk;
        pk.x = packbf2(acc[i4][j4][0], acc[i4][j4][1]);
        pk.y = packbf2(acc[i4][j4][2], acc[i4][j4][3]);
        *(uint2*)(Vt + (((size_t)(b * H_ + h)) * D_ + d) * S_ + s0) = pk;
      }
  } else {
    // SWAPPED: row = n-off = quad*4+reg, col = m-off = l16. RoPE pair (d,d+32)=(j4,j4+2).
    u16* dst = (which == 0) ? Q : K;
#pragma unroll
    for (int i4 = 0; i4 < 4; ++i4)
#pragma unroll
      for (int j4 = 0; j4 < 2; ++j4) {
        int m = mbase + wm * 64 + i4 * 16 + l16;
        int n1 = nbase + wn * 64 + j4 * 16 + quad * 4;
        int b = m >> 11, s = m & 2047;
        int h = n1 >> 6, d1 = n1 & 63;  // d1 in [0,32), multiple of 4
        float4 c4 = *(const float4*)(cos_t + s * 32 + d1);
        float4 s4 = *(const float4*)(sin_t + s * 32 + d1);
        float y1[4], y2[4];
#pragma unroll
        for (int r = 0; r < 4; ++r) {
          float cr = ((const float*)&c4)[r], sr = ((const float*)&s4)[r];
          float x1 = acc[i4][j4][r], x2 = acc[i4][j4 + 2][r];
          y1[r] = x1 * cr - x2 * sr;
          y2[r] = x2 * cr + x1 * sr;
        }
        size_t base = ((size_t)(b * H_ + h) * S_ + s) * D_;
        uint2 p1, p2;
        p1.x = packbf2(y1[0], y1[1]);
        p1.y = packbf2(y1[2], y1[3]);
        p2.x = packbf2(y2[0], y2[1]);
        p2.y = packbf2(y2[2], y2[3]);
        *(uint2*)(dst + base + d1) = p1;
        *(uint2*)(dst + base + d1 + 32) = p2;
      }
  }
}

// ---------- flash helpers ----------
// PV step for a 32-q wave: P frags for both 16-q blocks (wave-private LDS, in-order
// vs later writes) + V frags read ONCE and reused across both q-blocks.
__device__ __forceinline__ void pv_step(const char* Pw, const char* Vp, int quad, int l16,
                                        const bf16x8& ones, f32x4 (*o)[4], f32x4* lacc) {
  bf16x8 p[2][2];
#pragma unroll
  for (int qb = 0; qb < 2; ++qb) {
    const char* Pr = Pw + qb * 2048;
#pragma unroll
    for (int kh = 0; kh < 2; ++kh) {
      int c0 = kh * 8 + quad * 2;
      union { uint2 u[2]; bf16x8 v; } cv;
      cv.u[0] = *(const uint2*)(Pr + l16 * 128 + ((c0) ^ l16) * 8);
      cv.u[1] = *(const uint2*)(Pr + l16 * 128 + ((c0 + 1) ^ l16) * 8);
      p[qb][kh] = cv.v;
    }
    lacc[qb] = __builtin_amdgcn_mfma_f32_16x16x32_bf16(p[qb][0], ones, lacc[qb], 0, 0, 0);
    lacc[qb] = __builtin_amdgcn_mfma_f32_16x16x32_bf16(p[qb][1], ones, lacc[qb], 0, 0, 0);
  }
#pragma unroll
  for (int jd = 0; jd < 4; ++jd) {
    int r = jd * 16 + l16;
#pragma unroll
    for (int kh = 0; kh < 2; ++kh) {
      int L = r * 8 + ((kh * 4 + quad) ^ (r & 7));
      bf16x8 vf = *(const bf16x8*)(Vp + L * 16);
      o[0][jd] = __builtin_amdgcn_mfma_f32_16x16x32_bf16(p[0][kh], vf, o[0][jd], 0, 0, 0);
      o[1][jd] = __builtin_amdgcn_mfma_f32_16x16x32_bf16(p[1][kh], vf, o[1][jd], 0, 0, 0);
    }
  }
}

// S^T = K * Q^T : row=key (quad*4+reg), col=q (l16). kf read once, 2 q-blocks.
__device__ __forceinline__ void qk_step(const char* Ks, const bf16x8 (*qfrag)[2], int quad,
                                        int l16, f32x4 (*s)[4]) {
#pragma unroll
  for (int jt = 0; jt < 4; ++jt) {
    int r = jt * 16 + l16;
#pragma unroll
    for (int kh = 0; kh < 2; ++kh) {
      int L = r * 8 + ((kh * 4 + quad) ^ (r & 7));
      bf16x8 kf = *(const bf16x8*)(Ks + L * 16);
      s[0][jt] = __builtin_amdgcn_mfma_f32_16x16x32_bf16(kf, qfrag[0][kh], s[0][jt], 0, 0, 0);
      s[1][jt] = __builtin_amdgcn_mfma_f32_16x16x32_bf16(kf, qfrag[1][kh], s[1][jt], 0, 0, 0);
    }
  }
}

// fixed-max softmax: exp2 + perm-pack (bf16 truncation); write P
__device__ __forceinline__ void softmax_store(const f32x4 (*s)[4], const float4* mv,
                                              char* Pw, int quad, int l16) {
#pragma unroll
  for (int qb = 0; qb < 2; ++qb)
#pragma unroll
    for (int jt = 0; jt < 4; ++jt) {
      float pf[4];
#pragma unroll
      for (int r = 0; r < 4; ++r) {
        float mvr = ((const float*)&mv[jt])[r];
        pf[r] = __builtin_amdgcn_exp2f(fmaf(s[qb][jt][r], SCALE_LOG2, mvr));
      }
      uint2 pk;
      pk.x = permpack(pf[0], pf[1]);
      pk.y = permpack(pf[2], pf[3]);
      int chunk = (jt * 4 + quad) ^ l16;
      *(uint2*)(Pw + qb * 2048 + l16 * 128 + chunk * 8) = pk;
    }
}

__device__ __forceinline__ void stage_kv(const u16* Kbase, const u16* Vbase, char* Kn,
                                         int nb, int tid) {
#pragma unroll
  for (int half = 0; half < 2; ++half) {
    int i = half * 256 + tid;
    int r = i >> 3, gs = i & 7, gsrc = gs ^ (r & 7);
    gl2lds16(Kbase + (size_t)(nb + r) * D_ + gsrc * 8, Kn + i * 16);
    gl2lds16(Vbase + (size_t)r * S_ + nb + gsrc * 8, Kn + 8192 + i * 16);
  }
}

// ---------------- Flash attention: 256 threads, 4 waves x 32 q ----------------
// grid (16, 32), 2 blocks/CU. 64-key tiles, triple-buffered K/V, single-buffer P,
// 1 barrier/tile. Steady iter kt: stage kt+1; PV(kt-1); QK(kt); softmax+write P(kt).
// First/last iterations peeled (branch-free steady body -> one scheduling region);
// s_setprio(1) wraps the MFMA-dense region (T5: 2 independent blocks/CU arbitrate).
__global__ __launch_bounds__(256, 2) void flash_kernel(
    const u16* __restrict__ Q, const u16* __restrict__ K, const u16* __restrict__ Vt,
    const float* __restrict__ mask2, float* __restrict__ out) {
  __shared__ char smem[65536];  // K/V: 3 bufs @ b*16384 (K@+0, V@+8192). P: @49152 + wave*4096.
  int tid = threadIdx.x, wave = tid >> 6;
  int lane = tid & 63;
  int quad = lane >> 4, l16 = lane & 15;
  int bh = blockIdx.y, b = bh >> 4, h = bh & 15;
  int qbase = blockIdx.x * 128;
  int qw = qbase + wave * 32;
  char* Pw = smem + 49152 + wave * 4096;
  const float* m2row = mask2 + b * S_;
  const u16* Kbase = K + (size_t)bh * S_ * D_;
  const u16* Vbase = Vt + (size_t)bh * D_ * S_;

  bf16x8 qfrag[2][2];
#pragma unroll
  for (int qb = 0; qb < 2; ++qb) {
    const u16* qp = Q + ((size_t)bh * S_ + qw + qb * 16 + l16) * D_ + quad * 8;
    qfrag[qb][0] = *(const bf16x8*)qp;
    qfrag[qb][1] = *(const bf16x8*)(qp + 32);
  }
  bf16x8 ones;
#pragma unroll
  for (int j = 0; j < 8; ++j) ones[j] = (short)0x3f80;  // bf16 1.0

  f32x4 o[2][4] = {};
  f32x4 lacc[2] = {};

  // stage tile 0 into buffer 0
  stage_kv(Kbase, Vbase, smem, 0, tid);
  // mask prefetch for kt=0 (per-key, indexed by jt*16 + quad*4 + r)
  float4 mv[4];
#pragma unroll
  for (int jt = 0; jt < 4; ++jt) mv[jt] = *(const float4*)(m2row + jt * 16 + quad * 4);

  // ---- kt = 0 (peeled: no PV) ----
  {
    __syncthreads();  // tile 0 staged
    stage_kv(Kbase, Vbase, smem + 16384, 64, tid);  // tile 1 -> buf 1
    f32x4 s[2][4] = {};
    __builtin_amdgcn_s_setprio(1);
    qk_step(smem, qfrag, quad, l16, s);
    __builtin_amdgcn_s_setprio(0);
    softmax_store(s, mv, Pw, quad, l16);
#pragma unroll
    for (int jt = 0; jt < 4; ++jt)
      mv[jt] = *(const float4*)(m2row + 64 + jt * 16 + quad * 4);
  }

  // ---- steady state kt = 1..30 (branch-free body) ----
  for (int kt = 1; kt <= 30; ++kt) {
    char* Ks = smem + (kt % 3) * 16384;
    __syncthreads();  // staging of tile kt complete; buf (kt+1)%3 free
    stage_kv(Kbase, Vbase, smem + ((kt + 1) % 3) * 16384, (kt + 1) * 64, tid);

    __builtin_amdgcn_s_setprio(1);
    // PV for tile kt-1 (P reads precede this iter's P writes -> in-order safe)
    const char* Vp = smem + ((kt - 1) % 3) * 16384 + 8192;
    pv_step(Pw, Vp, quad, l16, ones, o, lacc);

    f32x4 s[2][4] = {};
    qk_step(Ks, qfrag, quad, l16, s);
    __builtin_amdgcn_s_setprio(0);

    softmax_store(s, mv, Pw, quad, l16);
#pragma unroll
    for (int jt = 0; jt < 4; ++jt)
      mv[jt] = *(const float4*)(m2row + (kt + 1) * 64 + jt * 16 + quad * 4);
  }

  // ---- kt = 31 (peeled: no stage, no mask prefetch) ----
  {
    __syncthreads();
    __builtin_amdgcn_s_setprio(1);
    pv_step(Pw, smem + 0 * 16384 + 8192, quad, l16, ones, o, lacc);  // PV(30), buf 0
    f32x4 s[2][4] = {};
    qk_step(smem + 16384, qfrag, quad, l16, s);  // tile 31 in buf 1
    __builtin_amdgcn_s_setprio(0);
    softmax_store(s, mv, Pw, quad, l16);
  }

  // drain: PV for tile 31 (V in buf 31%3 = 1)
  pv_step(Pw, smem + 16384 + 8192, quad, l16, ones, o, lacc);

  // epilogue: lacc[qb][r] holds the full row-sum for q = qw + qb*16 + quad*4 + r
  float inv[2][4];
#pragma unroll
  for (int qb = 0; qb < 2; ++qb)
#pragma unroll
    for (int r = 0; r < 4; ++r) inv[qb][r] = 1.0f / lacc[qb][r];
#pragma unroll
  for (int qb = 0; qb < 2; ++qb)
#pragma unroll
    for (int jd = 0; jd < 4; ++jd) {
#pragma unroll
      for (int r = 0; r < 4; ++r) {
        int d = jd * 16 + l16;
        int q = qw + qb * 16 + quad * 4 + r;
        out[(((size_t)b * S_ + q) * H_ + h) * D_ + d] = o[qb][jd][r] * inv[qb][r];
      }
    }
}

extern "C" void kernel_launch(void* const* d_in, const int* in_sizes, int n_in,
                              void* d_out, int out_size, void* d_ws, size_t ws_size,
                              hipStream_t stream) {
  const float* hid = (const float*)d_in[0];
  const float* mask = (const float*)d_in[1];
  const float* Wq = (const float*)d_in[2];
  const float* Wk = (const float*)d_in[3];
  const float* Wv = (const float*)d_in[4];
  float* out = (float*)d_out;
  char* ws = (char*)d_ws;

  u16* Xbf = (u16*)ws;                              // 8 MB
  u16* Wqb = (u16*)(ws + (8u << 20));               // 2 MB
  u16* Wkb = (u16*)(ws + (10u << 20));              // 2 MB
  u16* Wvb = (u16*)(ws + (12u << 20));              // 2 MB
  u16* Qb = (u16*)(ws + (14u << 20));               // 8 MB (BH,S,D)
  u16* Kb = (u16*)(ws + (22u << 20));               // 8 MB (BH,S,D)
  u16* Vtb = (u16*)(ws + (30u << 20));              // 8 MB (BH,D,S)
  float* cos_t = (float*)(ws + (38u << 20));        // 256 KB
  float* sin_t = (float*)(ws + (38u << 20) + (256u << 10));
  float* mask2 = (float*)(ws + (38u << 20) + (512u << 10));  // 16 KB

  prep_kernel<<<7440, 256, 0, stream>>>(hid, Wq, Wk, Wv, mask, Xbf, Wqb, Wkb, Wvb,
                                        cos_t, sin_t, mask2);
  qkv_gemm_kernel<<<dim3(24, 32), 256, 0, stream>>>(Xbf, Wqb, Wkb, Wvb, cos_t, sin_t,
                                                    Qb, Kb, Vtb);
  flash_kernel<<<dim3(16, 32), 256, 0, stream>>>(Qb, Kb, Vtb, mask2, out);
}

// Round 3
// 180.051 us; speedup vs baseline: 1.0949x; 1.0949x over previous
//
#include <hip/hip_runtime.h>
#include <stdint.h>

typedef unsigned short u16;
typedef short bf16x8 __attribute__((ext_vector_type(8)));
typedef float f32x4 __attribute__((ext_vector_type(4)));

#define S_ 2048
#define HID_ 1024
#define H_ 16
#define D_ 64

#define LOG2E 1.4426950408889634f
#define SCALE_LOG2 0.18033688011112042f   /* 0.125 * log2(e) */
#define MAXC_LOG2 11.541560327111707f     /* 8 * log2(e) */

__device__ __forceinline__ u16 f2bf(float f) {
  uint32_t x = __builtin_bit_cast(uint32_t, f);
  uint32_t r = (x + 0x7fffu + ((x >> 16) & 1u)) >> 16;
  return (u16)r;
}
__device__ __forceinline__ uint32_t packbf2(float a, float b) {
  return (uint32_t)f2bf(a) | ((uint32_t)f2bf(b) << 16);
}
// truncating pack: low16 = bf16(a), high16 = bf16(b), one v_perm_b32
__device__ __forceinline__ uint32_t permpack(float a, float b) {
  return __builtin_amdgcn_perm(__builtin_bit_cast(uint32_t, b),
                               __builtin_bit_cast(uint32_t, a), 0x07060302u);
}

__device__ __forceinline__ void gl2lds16(const void* g, void* l) {
  __builtin_amdgcn_global_load_lds(
      (const __attribute__((address_space(1))) unsigned int*)g,
      (__attribute__((address_space(3))) unsigned int*)l, 16, 0, 0);
}

// ------------- prep: converts + RoPE tables + mask2, one kernel -------------
#define NX_ (1 << 20)
#define NW_ (1 << 18)
#define NROPE_ 65536
__global__ void prep_kernel(const float* __restrict__ X, const float* __restrict__ Wq,
                            const float* __restrict__ Wk, const float* __restrict__ Wv,
                            const float* __restrict__ mask, u16* __restrict__ Xb,
                            u16* __restrict__ Wqb, u16* __restrict__ Wkb,
                            u16* __restrict__ Wvb, float* __restrict__ cos_t,
                            float* __restrict__ sin_t, float* __restrict__ mask2) {
  int i = blockIdx.x * 256 + threadIdx.x;
  if (i < NX_ + 3 * NW_) {
    const float* src;
    u16* dst;
    int off;
    if (i < NX_) {
      src = X; dst = Xb; off = i;
    } else if (i < NX_ + NW_) {
      src = Wq; dst = Wqb; off = i - NX_;
    } else if (i < NX_ + 2 * NW_) {
      src = Wk; dst = Wkb; off = i - NX_ - NW_;
    } else {
      src = Wv; dst = Wvb; off = i - NX_ - 2 * NW_;
    }
    float4 v = ((const float4*)src)[off];
    uint2 packed;
    packed.x = packbf2(v.x, v.y);
    packed.y = packbf2(v.z, v.w);
    ((uint2*)dst)[off] = packed;
  } else if (i < NX_ + 3 * NW_ + NROPE_) {
    int t = i - (NX_ + 3 * NW_);  // 65536 = 2048*32
    int s = t >> 5, j = t & 31;
    float invf = powf(10000.0f, -(float)j * (1.0f / 32.0f));
    float ang = (float)s * invf;
    cos_t[t] = cosf(ang);
    sin_t[t] = sinf(ang);
  } else {
    int t = i - (NX_ + 3 * NW_ + NROPE_);  // 4096 = 2*2048
    mask2[t] = fmaf(mask[t], LOG2E, -MAXC_LOG2);
  }
}

// ---------------- QKV GEMM: BK=32 double-buffer, 32 KB LDS, 3 blocks/CU ----------------
// C = X(4096x1024) * W^T. 128x128 tile, BK=32, 4 waves 2x2.
// grid.x in [0,24): which = x>>3 (0:Q 1:K 2:V), nbase = (x&7)*128.
// Stage-BEFORE-compute dbuf (loads covered by compute; round-2's stage-after regressed).
// 32 KB LDS -> 3 blocks/CU -> all 768 blocks co-resident (no 1.5-wave dispatch tail).
// LDS layout: row-pair lines of 8 chunks, slot = (c + 4*(r&1)) ^ ((r>>1)&7)
// -> exactly 2 lanes per 16B slot on frag reads (conflict-free); staging keeps
// linear LDS dest + inverse-permuted GLOBAL source (m173 both-sides rule).
__global__ __launch_bounds__(256, 3) void qkv_gemm_kernel(
    const u16* __restrict__ X, const u16* __restrict__ Wq, const u16* __restrict__ Wk,
    const u16* __restrict__ Wv, const float* __restrict__ cos_t,
    const float* __restrict__ sin_t, u16* __restrict__ Q, u16* __restrict__ K,
    u16* __restrict__ Vt) {
  __shared__ char smem[32768];  // buf b: A @ b*16384, B @ b*16384+8192
  int tid = threadIdx.x;
  int lane = tid & 63, wave = tid >> 6;
  int wm = wave >> 1, wn = wave & 1;
  int quad = lane >> 4, l16 = lane & 15;
  int which = blockIdx.x >> 3;
  int nbase = (blockIdx.x & 7) * 128;
  int mbase = blockIdx.y * 128;
  const u16* W = (which == 0) ? Wq : (which == 1) ? Wk : Wv;

  // stage tile 0 into buffer 0 (512 chunks each of A and B; 2 per thread)
#pragma unroll
  for (int it = 0; it < 2; ++it) {
    int i = it * 256 + tid;
    int line = i >> 3, g = i & 7;
    int cp = g ^ (line & 7);
    int r = line * 2 + (cp >> 2), cc = (cp & 3) * 8;
    gl2lds16(X + (size_t)(mbase + r) * HID_ + cc, smem + i * 16);
    gl2lds16(W + (size_t)(nbase + r) * HID_ + cc, smem + 8192 + i * 16);
  }

  f32x4 acc[4][4] = {};

  for (int kk = 0; kk < 32; ++kk) {
    const char* As = smem + (kk & 1) * 16384;
    const char* Bs = As + 8192;
    __syncthreads();  // staging of tile kk complete (per-wave vmcnt drain + join)

    if (kk < 31) {  // stage tile kk+1 into the other buffer (reads of kk-1 done)
      int k0n = (kk + 1) * 32;
      char* An = smem + ((kk + 1) & 1) * 16384;
#pragma unroll
      for (int it = 0; it < 2; ++it) {
        int i = it * 256 + tid;
        int line = i >> 3, g = i & 7;
        int cp = g ^ (line & 7);
        int r = line * 2 + (cp >> 2), cc = (cp & 3) * 8;
        gl2lds16(X + (size_t)(mbase + r) * HID_ + k0n + cc, An + i * 16);
        gl2lds16(W + (size_t)(nbase + r) * HID_ + k0n + cc, An + 8192 + i * 16);
      }
    }

    bf16x8 afrag[4], bfrag[4];
#pragma unroll
    for (int i4 = 0; i4 < 4; ++i4) {
      int r = wm * 64 + i4 * 16 + l16;
      int slot = (quad + ((r & 1) << 2)) ^ ((r >> 1) & 7);
      afrag[i4] = *(const bf16x8*)(As + (r >> 1) * 128 + slot * 16);
    }
#pragma unroll
    for (int j4 = 0; j4 < 4; ++j4) {
      int r = wn * 64 + j4 * 16 + l16;
      int slot = (quad + ((r & 1) << 2)) ^ ((r >> 1) & 7);
      bfrag[j4] = *(const bf16x8*)(Bs + (r >> 1) * 128 + slot * 16);
    }
    if (which == 2) {
#pragma unroll
      for (int i4 = 0; i4 < 4; ++i4)
#pragma unroll
        for (int j4 = 0; j4 < 4; ++j4)
          acc[i4][j4] = __builtin_amdgcn_mfma_f32_16x16x32_bf16(afrag[i4], bfrag[j4],
                                                                acc[i4][j4], 0, 0, 0);
    } else {
#pragma unroll
      for (int i4 = 0; i4 < 4; ++i4)
#pragma unroll
        for (int j4 = 0; j4 < 4; ++j4)
          acc[i4][j4] = __builtin_amdgcn_mfma_f32_16x16x32_bf16(bfrag[j4], afrag[i4],
                                                                acc[i4][j4], 0, 0, 0);
    }
  }

  if (which == 2) {
    // C tile: row = m-off = quad*4+reg, col = n-off = l16. 4 regs = 4 consecutive s.
#pragma unroll
    for (int i4 = 0; i4 < 4; ++i4)
#pragma unroll
      for (int j4 = 0; j4 < 4; ++j4) {
        int m = mbase + wm * 64 + i4 * 16 + quad * 4;
        int n = nbase + wn * 64 + j4 * 16 + l16;
        int b = m >> 11, s0 = m & 2047;
        int h = n >> 6, d = n & 63;
        uint2 pk;
        pk.x = packbf2(acc[i4][j4][0], acc[i4][j4][1]);
        pk.y = packbf2(acc[i4][j4][2], acc[i4][j4][3]);
        *(uint2*)(Vt + (((size_t)(b * H_ + h)) * D_ + d) * S_ + s0) = pk;
      }
  } else {
    // SWAPPED: row = n-off = quad*4+reg, col = m-off = l16. RoPE pair (d,d+32)=(j4,j4+2).
    u16* dst = (which == 0) ? Q : K;
#pragma unroll
    for (int i4 = 0; i4 < 4; ++i4)
#pragma unroll
      for (int j4 = 0; j4 < 2; ++j4) {
        int m = mbase + wm * 64 + i4 * 16 + l16;
        int n1 = nbase + wn * 64 + j4 * 16 + quad * 4;
        int b = m >> 11, s = m & 2047;
        int h = n1 >> 6, d1 = n1 & 63;  // d1 in [0,32), multiple of 4
        float4 c4 = *(const float4*)(cos_t + s * 32 + d1);
        float4 s4 = *(const float4*)(sin_t + s * 32 + d1);
        float y1[4], y2[4];
#pragma unroll
        for (int r = 0; r < 4; ++r) {
          float cr = ((const float*)&c4)[r], sr = ((const float*)&s4)[r];
          float x1 = acc[i4][j4][r], x2 = acc[i4][j4 + 2][r];
          y1[r] = x1 * cr - x2 * sr;
          y2[r] = x2 * cr + x1 * sr;
        }
        size_t base = ((size_t)(b * H_ + h) * S_ + s) * D_;
        uint2 p1, p2;
        p1.x = packbf2(y1[0], y1[1]);
        p1.y = packbf2(y1[2], y1[3]);
        p2.x = packbf2(y2[0], y2[1]);
        p2.y = packbf2(y2[2], y2[3]);
        *(uint2*)(dst + base + d1) = p1;
        *(uint2*)(dst + base + d1 + 32) = p2;
      }
  }
}

// ---------- flash helpers ----------
// PV step for a 32-q wave: P frags for both 16-q blocks (wave-private LDS, in-order
// vs later writes) + V frags read ONCE and reused across both q-blocks.
__device__ __forceinline__ void pv_step(const char* Pw, const char* Vp, int quad, int l16,
                                        const bf16x8& ones, f32x4 (*o)[4], f32x4* lacc) {
  bf16x8 p[2][2];
#pragma unroll
  for (int qb = 0; qb < 2; ++qb) {
    const char* Pr = Pw + qb * 2048;
#pragma unroll
    for (int kh = 0; kh < 2; ++kh) {
      int c0 = kh * 8 + quad * 2;
      union { uint2 u[2]; bf16x8 v; } cv;
      cv.u[0] = *(const uint2*)(Pr + l16 * 128 + ((c0) ^ l16) * 8);
      cv.u[1] = *(const uint2*)(Pr + l16 * 128 + ((c0 + 1) ^ l16) * 8);
      p[qb][kh] = cv.v;
    }
    lacc[qb] = __builtin_amdgcn_mfma_f32_16x16x32_bf16(p[qb][0], ones, lacc[qb], 0, 0, 0);
    lacc[qb] = __builtin_amdgcn_mfma_f32_16x16x32_bf16(p[qb][1], ones, lacc[qb], 0, 0, 0);
  }
#pragma unroll
  for (int jd = 0; jd < 4; ++jd) {
    int r = jd * 16 + l16;
#pragma unroll
    for (int kh = 0; kh < 2; ++kh) {
      int L = r * 8 + ((kh * 4 + quad) ^ (r & 7));
      bf16x8 vf = *(const bf16x8*)(Vp + L * 16);
      o[0][jd] = __builtin_amdgcn_mfma_f32_16x16x32_bf16(p[0][kh], vf, o[0][jd], 0, 0, 0);
      o[1][jd] = __builtin_amdgcn_mfma_f32_16x16x32_bf16(p[1][kh], vf, o[1][jd], 0, 0, 0);
    }
  }
}

// S^T = K * Q^T : row=key (quad*4+reg), col=q (l16). kf read once, 2 q-blocks.
__device__ __forceinline__ void qk_step(const char* Ks, const bf16x8 (*qfrag)[2], int quad,
                                        int l16, f32x4 (*s)[4]) {
#pragma unroll
  for (int jt = 0; jt < 4; ++jt) {
    int r = jt * 16 + l16;
#pragma unroll
    for (int kh = 0; kh < 2; ++kh) {
      int L = r * 8 + ((kh * 4 + quad) ^ (r & 7));
      bf16x8 kf = *(const bf16x8*)(Ks + L * 16);
      s[0][jt] = __builtin_amdgcn_mfma_f32_16x16x32_bf16(kf, qfrag[0][kh], s[0][jt], 0, 0, 0);
      s[1][jt] = __builtin_amdgcn_mfma_f32_16x16x32_bf16(kf, qfrag[1][kh], s[1][jt], 0, 0, 0);
    }
  }
}

// fixed-max softmax: exp2 + perm-pack (bf16 truncation); write P
__device__ __forceinline__ void softmax_store(const f32x4 (*s)[4], const float4* mv,
                                              char* Pw, int quad, int l16) {
#pragma unroll
  for (int qb = 0; qb < 2; ++qb)
#pragma unroll
    for (int jt = 0; jt < 4; ++jt) {
      float pf[4];
#pragma unroll
      for (int r = 0; r < 4; ++r) {
        float mvr = ((const float*)&mv[jt])[r];
        pf[r] = __builtin_amdgcn_exp2f(fmaf(s[qb][jt][r], SCALE_LOG2, mvr));
      }
      uint2 pk;
      pk.x = permpack(pf[0], pf[1]);
      pk.y = permpack(pf[2], pf[3]);
      int chunk = (jt * 4 + quad) ^ l16;
      *(uint2*)(Pw + qb * 2048 + l16 * 128 + chunk * 8) = pk;
    }
}

__device__ __forceinline__ void stage_kv(const u16* Kbase, const u16* Vbase, char* Kn,
                                         int nb, int tid) {
#pragma unroll
  for (int half = 0; half < 2; ++half) {
    int i = half * 256 + tid;
    int r = i >> 3, gs = i & 7, gsrc = gs ^ (r & 7);
    gl2lds16(Kbase + (size_t)(nb + r) * D_ + gsrc * 8, Kn + i * 16);
    gl2lds16(Vbase + (size_t)r * S_ + nb + gsrc * 8, Kn + 8192 + i * 16);
  }
}

// ---------------- Flash attention: 256 threads, 4 waves x 32 q ----------------
// grid (16, 32), 2 blocks/CU. 64-key tiles, triple-buffered K/V, single-buffer P,
// 1 barrier/tile. Steady iter kt: stage kt+1; PV(kt-1); QK(kt); softmax+write P(kt).
// First/last iterations peeled (branch-free steady body -> one scheduling region);
// s_setprio(1) wraps the MFMA-dense region (T5: 2 independent blocks/CU arbitrate).
__global__ __launch_bounds__(256, 2) void flash_kernel(
    const u16* __restrict__ Q, const u16* __restrict__ K, const u16* __restrict__ Vt,
    const float* __restrict__ mask2, float* __restrict__ out) {
  __shared__ char smem[65536];  // K/V: 3 bufs @ b*16384 (K@+0, V@+8192). P: @49152 + wave*4096.
  int tid = threadIdx.x, wave = tid >> 6;
  int lane = tid & 63;
  int quad = lane >> 4, l16 = lane & 15;
  int bh = blockIdx.y, b = bh >> 4, h = bh & 15;
  int qbase = blockIdx.x * 128;
  int qw = qbase + wave * 32;
  char* Pw = smem + 49152 + wave * 4096;
  const float* m2row = mask2 + b * S_;
  const u16* Kbase = K + (size_t)bh * S_ * D_;
  const u16* Vbase = Vt + (size_t)bh * D_ * S_;

  bf16x8 qfrag[2][2];
#pragma unroll
  for (int qb = 0; qb < 2; ++qb) {
    const u16* qp = Q + ((size_t)bh * S_ + qw + qb * 16 + l16) * D_ + quad * 8;
    qfrag[qb][0] = *(const bf16x8*)qp;
    qfrag[qb][1] = *(const bf16x8*)(qp + 32);
  }
  bf16x8 ones;
#pragma unroll
  for (int j = 0; j < 8; ++j) ones[j] = (short)0x3f80;  // bf16 1.0

  f32x4 o[2][4] = {};
  f32x4 lacc[2] = {};

  // stage tile 0 into buffer 0
  stage_kv(Kbase, Vbase, smem, 0, tid);
  // mask prefetch for kt=0 (per-key, indexed by jt*16 + quad*4 + r)
  float4 mv[4];
#pragma unroll
  for (int jt = 0; jt < 4; ++jt) mv[jt] = *(const float4*)(m2row + jt * 16 + quad * 4);

  // ---- kt = 0 (peeled: no PV) ----
  {
    __syncthreads();  // tile 0 staged
    stage_kv(Kbase, Vbase, smem + 16384, 64, tid);  // tile 1 -> buf 1
    f32x4 s[2][4] = {};
    __builtin_amdgcn_s_setprio(1);
    qk_step(smem, qfrag, quad, l16, s);
    __builtin_amdgcn_s_setprio(0);
    softmax_store(s, mv, Pw, quad, l16);
#pragma unroll
    for (int jt = 0; jt < 4; ++jt)
      mv[jt] = *(const float4*)(m2row + 64 + jt * 16 + quad * 4);
  }

  // ---- steady state kt = 1..30 (branch-free body) ----
  for (int kt = 1; kt <= 30; ++kt) {
    char* Ks = smem + (kt % 3) * 16384;
    __syncthreads();  // staging of tile kt complete; buf (kt+1)%3 free
    stage_kv(Kbase, Vbase, smem + ((kt + 1) % 3) * 16384, (kt + 1) * 64, tid);

    __builtin_amdgcn_s_setprio(1);
    // PV for tile kt-1 (P reads precede this iter's P writes -> in-order safe)
    const char* Vp = smem + ((kt - 1) % 3) * 16384 + 8192;
    pv_step(Pw, Vp, quad, l16, ones, o, lacc);

    f32x4 s[2][4] = {};
    qk_step(Ks, qfrag, quad, l16, s);
    __builtin_amdgcn_s_setprio(0);

    softmax_store(s, mv, Pw, quad, l16);
#pragma unroll
    for (int jt = 0; jt < 4; ++jt)
      mv[jt] = *(const float4*)(m2row + (kt + 1) * 64 + jt * 16 + quad * 4);
  }

  // ---- kt = 31 (peeled: no stage, no mask prefetch) ----
  {
    __syncthreads();
    __builtin_amdgcn_s_setprio(1);
    pv_step(Pw, smem + 0 * 16384 + 8192, quad, l16, ones, o, lacc);  // PV(30), buf 0
    f32x4 s[2][4] = {};
    qk_step(smem + 16384, qfrag, quad, l16, s);  // tile 31 in buf 1
    __builtin_amdgcn_s_setprio(0);
    softmax_store(s, mv, Pw, quad, l16);
  }

  // drain: PV for tile 31 (V in buf 31%3 = 1)
  pv_step(Pw, smem + 16384 + 8192, quad, l16, ones, o, lacc);

  // epilogue: lacc[qb][r] holds the full row-sum for q = qw + qb*16 + quad*4 + r
  float inv[2][4];
#pragma unroll
  for (int qb = 0; qb < 2; ++qb)
#pragma unroll
    for (int r = 0; r < 4; ++r) inv[qb][r] = 1.0f / lacc[qb][r];
#pragma unroll
  for (int qb = 0; qb < 2; ++qb)
#pragma unroll
    for (int jd = 0; jd < 4; ++jd) {
#pragma unroll
      for (int r = 0; r < 4; ++r) {
        int d = jd * 16 + l16;
        int q = qw + qb * 16 + quad * 4 + r;
        out[(((size_t)b * S_ + q) * H_ + h) * D_ + d] = o[qb][jd][r] * inv[qb][r];
      }
    }
}

extern "C" void kernel_launch(void* const* d_in, const int* in_sizes, int n_in,
                              void* d_out, int out_size, void* d_ws, size_t ws_size,
                              hipStream_t stream) {
  const float* hid = (const float*)d_in[0];
  const float* mask = (const float*)d_in[1];
  const float* Wq = (const float*)d_in[2];
  const float* Wk = (const float*)d_in[3];
  const float* Wv = (const float*)d_in[4];
  float* out = (float*)d_out;
  char* ws = (char*)d_ws;

  u16* Xbf = (u16*)ws;                              // 8 MB
  u16* Wqb = (u16*)(ws + (8u << 20));               // 2 MB
  u16* Wkb = (u16*)(ws + (10u << 20));              // 2 MB
  u16* Wvb = (u16*)(ws + (12u << 20));              // 2 MB
  u16* Qb = (u16*)(ws + (14u << 20));               // 8 MB (BH,S,D)
  u16* Kb = (u16*)(ws + (22u << 20));               // 8 MB (BH,S,D)
  u16* Vtb = (u16*)(ws + (30u << 20));              // 8 MB (BH,D,S)
  float* cos_t = (float*)(ws + (38u << 20));        // 256 KB
  float* sin_t = (float*)(ws + (38u << 20) + (256u << 10));
  float* mask2 = (float*)(ws + (38u << 20) + (512u << 10));  // 16 KB

  prep_kernel<<<7440, 256, 0, stream>>>(hid, Wq, Wk, Wv, mask, Xbf, Wqb, Wkb, Wvb,
                                        cos_t, sin_t, mask2);
  qkv_gemm_kernel<<<dim3(24, 32), 256, 0, stream>>>(Xbf, Wqb, Wkb, Wvb, cos_t, sin_t,
                                                    Qb, Kb, Vtb);
  flash_kernel<<<dim3(16, 32), 256, 0, stream>>>(Qb, Kb, Vtb, mask2, out);
}

// Round 4
// 168.339 us; speedup vs baseline: 1.1711x; 1.0696x over previous
//
#include <hip/hip_runtime.h>
#include <stdint.h>

typedef unsigned short u16;
typedef short bf16x8 __attribute__((ext_vector_type(8)));
typedef float f32x4 __attribute__((ext_vector_type(4)));

#define S_ 2048
#define HID_ 1024
#define H_ 16
#define D_ 64

#define LOG2E 1.4426950408889634f
#define SCALE_LOG2 0.18033688011112042f   /* 0.125 * log2(e) */
#define MAXC_LOG2 11.541560327111707f     /* 8 * log2(e) */

__device__ __forceinline__ u16 f2bf(float f) {
  uint32_t x = __builtin_bit_cast(uint32_t, f);
  uint32_t r = (x + 0x7fffu + ((x >> 16) & 1u)) >> 16;
  return (u16)r;
}
__device__ __forceinline__ uint32_t packbf2(float a, float b) {
  return (uint32_t)f2bf(a) | ((uint32_t)f2bf(b) << 16);
}
// truncating pack: low16 = bf16(a), high16 = bf16(b), one v_perm_b32
__device__ __forceinline__ uint32_t permpack(float a, float b) {
  return __builtin_amdgcn_perm(__builtin_bit_cast(uint32_t, b),
                               __builtin_bit_cast(uint32_t, a), 0x07060302u);
}

__device__ __forceinline__ void gl2lds16(const void* g, void* l) {
  __builtin_amdgcn_global_load_lds(
      (const __attribute__((address_space(1))) unsigned int*)g,
      (__attribute__((address_space(3))) unsigned int*)l, 16, 0, 0);
}

// ------------- prep: converts + RoPE tables + mask2, one kernel -------------
#define NX_ (1 << 20)
#define NW_ (1 << 18)
#define NROPE_ 65536
__global__ void prep_kernel(const float* __restrict__ X, const float* __restrict__ Wq,
                            const float* __restrict__ Wk, const float* __restrict__ Wv,
                            const float* __restrict__ mask, u16* __restrict__ Xb,
                            u16* __restrict__ Wqb, u16* __restrict__ Wkb,
                            u16* __restrict__ Wvb, float* __restrict__ cos_t,
                            float* __restrict__ sin_t, float* __restrict__ mask2) {
  int i = blockIdx.x * 256 + threadIdx.x;
  if (i < NX_ + 3 * NW_) {
    const float* src;
    u16* dst;
    int off;
    if (i < NX_) {
      src = X; dst = Xb; off = i;
    } else if (i < NX_ + NW_) {
      src = Wq; dst = Wqb; off = i - NX_;
    } else if (i < NX_ + 2 * NW_) {
      src = Wk; dst = Wkb; off = i - NX_ - NW_;
    } else {
      src = Wv; dst = Wvb; off = i - NX_ - 2 * NW_;
    }
    float4 v = ((const float4*)src)[off];
    uint2 packed;
    packed.x = packbf2(v.x, v.y);
    packed.y = packbf2(v.z, v.w);
    ((uint2*)dst)[off] = packed;
  } else if (i < NX_ + 3 * NW_ + NROPE_) {
    int t = i - (NX_ + 3 * NW_);  // 65536 = 2048*32
    int s = t >> 5, j = t & 31;
    float invf = powf(10000.0f, -(float)j * (1.0f / 32.0f));
    float ang = (float)s * invf;
    cos_t[t] = cosf(ang);
    sin_t[t] = sinf(ang);
  } else {
    int t = i - (NX_ + 3 * NW_ + NROPE_);  // 4096 = 2*2048
    mask2[t] = fmaf(mask[t], LOG2E, -MAXC_LOG2);
  }
}

// ---------------- QKV GEMM (R0/R1 proven): X+W dbuf in LDS, 1 barrier/iter ----------------
// C = X(4096x1024) * W^T. 128x128 tile, BK=64, 4 waves 2x2.
// grid.x in [0,24): which = x>>3 (0:Q 1:K 2:V), nbase = (x&7)*128.
// which<2: SWAPPED mfma operands (C regs run along d) + fused RoPE.
__global__ __launch_bounds__(256) void qkv_gemm_kernel(
    const u16* __restrict__ X, const u16* __restrict__ Wq, const u16* __restrict__ Wk,
    const u16* __restrict__ Wv, const float* __restrict__ cos_t,
    const float* __restrict__ sin_t, u16* __restrict__ Q, u16* __restrict__ K,
    u16* __restrict__ Vt) {
  __shared__ char smem[65536];  // As[2] @ 0/16K, Bs[2] @ 32K/48K
  int tid = threadIdx.x;
  int lane = tid & 63, wave = tid >> 6;
  int wm = wave >> 1, wn = wave & 1;
  int quad = lane >> 4, l16 = lane & 15;
  int which = blockIdx.x >> 3;
  int nbase = (blockIdx.x & 7) * 128;
  int mbase = blockIdx.y * 128;
  const u16* W = (which == 0) ? Wq : (which == 1) ? Wk : Wv;

  // stage tile 0 into buffer 0
#pragma unroll
  for (int it = 0; it < 4; ++it) {
    int i = it * 256 + tid;
    int r = i >> 3, gs = i & 7, gsrc = gs ^ (r & 7);
    gl2lds16(X + (size_t)(mbase + r) * HID_ + gsrc * 8, smem + i * 16);
    gl2lds16(W + (size_t)(nbase + r) * HID_ + gsrc * 8, smem + 32768 + i * 16);
  }

  f32x4 acc[4][4] = {};

  for (int kk = 0; kk < 16; ++kk) {
    char* As = smem + (kk & 1) * 16384;
    char* Bs = smem + 32768 + (kk & 1) * 16384;
    __syncthreads();  // staging of current buffer complete

    if (kk < 15) {  // prefetch next tile into other buffer
      int k0n = (kk + 1) * 64;
      char* An = smem + ((kk + 1) & 1) * 16384;
      char* Bn = smem + 32768 + ((kk + 1) & 1) * 16384;
#pragma unroll
      for (int it = 0; it < 4; ++it) {
        int i = it * 256 + tid;
        int r = i >> 3, gs = i & 7, gsrc = gs ^ (r & 7);
        gl2lds16(X + (size_t)(mbase + r) * HID_ + k0n + gsrc * 8, An + i * 16);
        gl2lds16(W + (size_t)(nbase + r) * HID_ + k0n + gsrc * 8, Bn + i * 16);
      }
    }

#pragma unroll
    for (int kh = 0; kh < 2; ++kh) {
      bf16x8 afrag[4], bfrag[4];
#pragma unroll
      for (int i4 = 0; i4 < 4; ++i4) {
        int r = wm * 64 + i4 * 16 + l16;
        int L = r * 8 + ((kh * 4 + quad) ^ (r & 7));
        afrag[i4] = *(const bf16x8*)(As + L * 16);
      }
#pragma unroll
      for (int j4 = 0; j4 < 4; ++j4) {
        int r = wn * 64 + j4 * 16 + l16;
        int L = r * 8 + ((kh * 4 + quad) ^ (r & 7));
        bfrag[j4] = *(const bf16x8*)(Bs + L * 16);
      }
      if (which == 2) {
#pragma unroll
        for (int i4 = 0; i4 < 4; ++i4)
#pragma unroll
          for (int j4 = 0; j4 < 4; ++j4)
            acc[i4][j4] = __builtin_amdgcn_mfma_f32_16x16x32_bf16(afrag[i4], bfrag[j4],
                                                                  acc[i4][j4], 0, 0, 0);
      } else {
#pragma unroll
        for (int i4 = 0; i4 < 4; ++i4)
#pragma unroll
          for (int j4 = 0; j4 < 4; ++j4)
            acc[i4][j4] = __builtin_amdgcn_mfma_f32_16x16x32_bf16(bfrag[j4], afrag[i4],
                                                                  acc[i4][j4], 0, 0, 0);
      }
    }
  }

  if (which == 2) {
    // C tile: row = m-off = quad*4+reg, col = n-off = l16. 4 regs = 4 consecutive s.
#pragma unroll
    for (int i4 = 0; i4 < 4; ++i4)
#pragma unroll
      for (int j4 = 0; j4 < 4; ++j4) {
        int m = mbase + wm * 64 + i4 * 16 + quad * 4;
        int n = nbase + wn * 64 + j4 * 16 + l16;
        int b = m >> 11, s0 = m & 2047;
        int h = n >> 6, d = n & 63;
        uint2 pk;
        pk.x = packbf2(acc[i4][j4][0], acc[i4][j4][1]);
        pk.y = packbf2(acc[i4][j4][2], acc[i4][j4][3]);
        *(uint2*)(Vt + (((size_t)(b * H_ + h)) * D_ + d) * S_ + s0) = pk;
      }
  } else {
    // SWAPPED: row = n-off = quad*4+reg, col = m-off = l16. RoPE pair (d,d+32)=(j4,j4+2).
    u16* dst = (which == 0) ? Q : K;
#pragma unroll
    for (int i4 = 0; i4 < 4; ++i4)
#pragma unroll
      for (int j4 = 0; j4 < 2; ++j4) {
        int m = mbase + wm * 64 + i4 * 16 + l16;
        int n1 = nbase + wn * 64 + j4 * 16 + quad * 4;
        int b = m >> 11, s = m & 2047;
        int h = n1 >> 6, d1 = n1 & 63;  // d1 in [0,32), multiple of 4
        float4 c4 = *(const float4*)(cos_t + s * 32 + d1);
        float4 s4 = *(const float4*)(sin_t + s * 32 + d1);
        float y1[4], y2[4];
#pragma unroll
        for (int r = 0; r < 4; ++r) {
          float cr = ((const float*)&c4)[r], sr = ((const float*)&s4)[r];
          float x1 = acc[i4][j4][r], x2 = acc[i4][j4 + 2][r];
          y1[r] = x1 * cr - x2 * sr;
          y2[r] = x2 * cr + x1 * sr;
        }
        size_t base = ((size_t)(b * H_ + h) * S_ + s) * D_;
        uint2 p1, p2;
        p1.x = packbf2(y1[0], y1[1]);
        p1.y = packbf2(y1[2], y1[3]);
        p2.x = packbf2(y2[0], y2[1]);
        p2.y = packbf2(y2[2], y2[3]);
        *(uint2*)(dst + base + d1) = p1;
        *(uint2*)(dst + base + d1 + 32) = p2;
      }
  }
}

// ---------- flash helpers ----------
// PV step: P fragments come from REGISTERS (pp), V frags from LDS (read once,
// reused across both q-blocks).
__device__ __forceinline__ void pv_step(const bf16x8 (*pp)[2], const char* Vp, int quad,
                                        int l16, const bf16x8& ones, f32x4 (*o)[4],
                                        f32x4* lacc) {
  lacc[0] = __builtin_amdgcn_mfma_f32_16x16x32_bf16(pp[0][0], ones, lacc[0], 0, 0, 0);
  lacc[0] = __builtin_amdgcn_mfma_f32_16x16x32_bf16(pp[0][1], ones, lacc[0], 0, 0, 0);
  lacc[1] = __builtin_amdgcn_mfma_f32_16x16x32_bf16(pp[1][0], ones, lacc[1], 0, 0, 0);
  lacc[1] = __builtin_amdgcn_mfma_f32_16x16x32_bf16(pp[1][1], ones, lacc[1], 0, 0, 0);
#pragma unroll
  for (int jd = 0; jd < 4; ++jd) {
    int r = jd * 16 + l16;
#pragma unroll
    for (int kh = 0; kh < 2; ++kh) {
      int L = r * 8 + ((kh * 4 + quad) ^ (r & 7));
      bf16x8 vf = *(const bf16x8*)(Vp + L * 16);
      o[0][jd] = __builtin_amdgcn_mfma_f32_16x16x32_bf16(pp[0][kh], vf, o[0][jd], 0, 0, 0);
      o[1][jd] = __builtin_amdgcn_mfma_f32_16x16x32_bf16(pp[1][kh], vf, o[1][jd], 0, 0, 0);
    }
  }
}

// S^T = K * Q^T : row=key (quad*4+reg), col=q (l16). kf read once, 2 q-blocks.
__device__ __forceinline__ void qk_step(const char* Ks, const bf16x8 (*qfrag)[2], int quad,
                                        int l16, f32x4 (*s)[4]) {
#pragma unroll
  for (int jt = 0; jt < 4; ++jt) {
    int r = jt * 16 + l16;
#pragma unroll
    for (int kh = 0; kh < 2; ++kh) {
      int L = r * 8 + ((kh * 4 + quad) ^ (r & 7));
      bf16x8 kf = *(const bf16x8*)(Ks + L * 16);
      s[0][jt] = __builtin_amdgcn_mfma_f32_16x16x32_bf16(kf, qfrag[0][kh], s[0][jt], 0, 0, 0);
      s[1][jt] = __builtin_amdgcn_mfma_f32_16x16x32_bf16(kf, qfrag[1][kh], s[1][jt], 0, 0, 0);
    }
  }
}

// fixed-max softmax (exp2 + truncating perm-pack), then IN-REGISTER q<->key
// transpose via permlane swaps (replaces the P LDS round-trip).
// Source u32 a[jt][i] @ srcquad s holds P[q=l16][keys jt*16+s*4+2i..+1].
// permlane32_swap(a[2kh],a[2kh+1]) then permlane16_swap gives the PV A-operand
// u32s T[kh][m] @ quad p = keys kh*32+p*8+2m..+1 (element-verified mapping).
__device__ __forceinline__ void softmax_pack(const f32x4 (*s)[4], const float4* mv,
                                             bf16x8 (*pp)[2]) {
#pragma unroll
  for (int qb = 0; qb < 2; ++qb) {
    uint32_t a[4][2];
#pragma unroll
    for (int jt = 0; jt < 4; ++jt) {
      float pf[4];
#pragma unroll
      for (int r = 0; r < 4; ++r) {
        float mvr = ((const float*)&mv[jt])[r];
        pf[r] = __builtin_amdgcn_exp2f(fmaf(s[qb][jt][r], SCALE_LOG2, mvr));
      }
      a[jt][0] = permpack(pf[0], pf[1]);
      a[jt][1] = permpack(pf[2], pf[3]);
    }
#pragma unroll
    for (int kh = 0; kh < 2; ++kh) {
      uint32_t tt[4];
#pragma unroll
      for (int i = 0; i < 2; ++i) {
        auto r1 = __builtin_amdgcn_permlane32_swap(a[2 * kh][i], a[2 * kh + 1][i],
                                                   false, false);
        auto r2 = __builtin_amdgcn_permlane16_swap(r1[0], r1[1], false, false);
        tt[i] = r2[0];      // T[kh][0+i]
        tt[2 + i] = r2[1];  // T[kh][2+i]
      }
      union { uint32_t u[4]; bf16x8 v; } cv;
      cv.u[0] = tt[0]; cv.u[1] = tt[1]; cv.u[2] = tt[2]; cv.u[3] = tt[3];
      pp[qb][kh] = cv.v;
    }
  }
}

__device__ __forceinline__ void stage_kv(const u16* Kbase, const u16* Vbase, char* Kn,
                                         int nb, int tid) {
#pragma unroll
  for (int half = 0; half < 2; ++half) {
    int i = half * 256 + tid;
    int r = i >> 3, gs = i & 7, gsrc = gs ^ (r & 7);
    gl2lds16(Kbase + (size_t)(nb + r) * D_ + gsrc * 8, Kn + i * 16);
    gl2lds16(Vbase + (size_t)r * S_ + nb + gsrc * 8, Kn + 8192 + i * 16);
  }
}

// ---------------- Flash attention: 256 threads, 4 waves x 32 q ----------------
// grid (16, 32), 2 blocks/CU. 64-key tiles, triple-buffered K/V (48 KB LDS),
// P entirely in registers (permlane transpose), 1 barrier/tile.
// Steady iter kt: stage kt+1; PV(kt-1) from pp regs; QK(kt); softmax+permlane -> pp.
__global__ __launch_bounds__(256, 2) void flash_kernel(
    const u16* __restrict__ Q, const u16* __restrict__ K, const u16* __restrict__ Vt,
    const float* __restrict__ mask2, float* __restrict__ out) {
  __shared__ char smem[49152];  // K/V: 3 bufs @ b*16384 (K@+0, V@+8192)
  int tid = threadIdx.x, wave = tid >> 6;
  int lane = tid & 63;
  int quad = lane >> 4, l16 = lane & 15;
  int bh = blockIdx.y, b = bh >> 4, h = bh & 15;
  int qbase = blockIdx.x * 128;
  int qw = qbase + wave * 32;
  const float* m2row = mask2 + b * S_;
  const u16* Kbase = K + (size_t)bh * S_ * D_;
  const u16* Vbase = Vt + (size_t)bh * D_ * S_;

  bf16x8 qfrag[2][2];
#pragma unroll
  for (int qb = 0; qb < 2; ++qb) {
    const u16* qp = Q + ((size_t)bh * S_ + qw + qb * 16 + l16) * D_ + quad * 8;
    qfrag[qb][0] = *(const bf16x8*)qp;
    qfrag[qb][1] = *(const bf16x8*)(qp + 32);
  }
  bf16x8 ones;
#pragma unroll
  for (int j = 0; j < 8; ++j) ones[j] = (short)0x3f80;  // bf16 1.0

  f32x4 o[2][4] = {};
  f32x4 lacc[2] = {};
  bf16x8 pp[2][2];  // P(kt) fragments, consumed by PV in iter kt+1

  // stage tile 0 into buffer 0
  stage_kv(Kbase, Vbase, smem, 0, tid);
  // mask prefetch for kt=0 (per-key, indexed by jt*16 + quad*4 + r)
  float4 mv[4];
#pragma unroll
  for (int jt = 0; jt < 4; ++jt) mv[jt] = *(const float4*)(m2row + jt * 16 + quad * 4);

  // ---- kt = 0 (peeled: no PV) ----
  {
    __syncthreads();  // tile 0 staged
    stage_kv(Kbase, Vbase, smem + 16384, 64, tid);  // tile 1 -> buf 1
    f32x4 s[2][4] = {};
    __builtin_amdgcn_s_setprio(1);
    qk_step(smem, qfrag, quad, l16, s);
    __builtin_amdgcn_s_setprio(0);
    softmax_pack(s, mv, pp);
#pragma unroll
    for (int jt = 0; jt < 4; ++jt)
      mv[jt] = *(const float4*)(m2row + 64 + jt * 16 + quad * 4);
  }

  // ---- steady state kt = 1..30 ----
  for (int kt = 1; kt <= 30; ++kt) {
    char* Ks = smem + (kt % 3) * 16384;
    __syncthreads();  // staging of tile kt complete; buf (kt+1)%3 free (PV(kt-2) done)
    stage_kv(Kbase, Vbase, smem + ((kt + 1) % 3) * 16384, (kt + 1) * 64, tid);

    __builtin_amdgcn_s_setprio(1);
    // PV for tile kt-1 from pp regs + V in buf (kt-1)%3
    const char* Vp = smem + ((kt - 1) % 3) * 16384 + 8192;
    pv_step(pp, Vp, quad, l16, ones, o, lacc);

    f32x4 s[2][4] = {};
    qk_step(Ks, qfrag, quad, l16, s);
    __builtin_amdgcn_s_setprio(0);

    softmax_pack(s, mv, pp);  // overwrites pp with P(kt) (PV above already consumed it)
#pragma unroll
    for (int jt = 0; jt < 4; ++jt)
      mv[jt] = *(const float4*)(m2row + (kt + 1) * 64 + jt * 16 + quad * 4);
  }

  // ---- kt = 31 (peeled: no stage, no mask prefetch) ----
  {
    __syncthreads();
    __builtin_amdgcn_s_setprio(1);
    pv_step(pp, smem + 0 * 16384 + 8192, quad, l16, ones, o, lacc);  // PV(30), buf 0
    f32x4 s[2][4] = {};
    qk_step(smem + 16384, qfrag, quad, l16, s);  // tile 31 in buf 1
    __builtin_amdgcn_s_setprio(0);
    softmax_pack(s, mv, pp);
  }

  // drain: PV for tile 31 (V in buf 31%3 = 1)
  pv_step(pp, smem + 16384 + 8192, quad, l16, ones, o, lacc);

  // epilogue: lacc[qb][r] holds the full row-sum for q = qw + qb*16 + quad*4 + r
  float inv[2][4];
#pragma unroll
  for (int qb = 0; qb < 2; ++qb)
#pragma unroll
    for (int r = 0; r < 4; ++r) inv[qb][r] = 1.0f / lacc[qb][r];
#pragma unroll
  for (int qb = 0; qb < 2; ++qb)
#pragma unroll
    for (int jd = 0; jd < 4; ++jd) {
#pragma unroll
      for (int r = 0; r < 4; ++r) {
        int d = jd * 16 + l16;
        int q = qw + qb * 16 + quad * 4 + r;
        out[(((size_t)b * S_ + q) * H_ + h) * D_ + d] = o[qb][jd][r] * inv[qb][r];
      }
    }
}

extern "C" void kernel_launch(void* const* d_in, const int* in_sizes, int n_in,
                              void* d_out, int out_size, void* d_ws, size_t ws_size,
                              hipStream_t stream) {
  const float* hid = (const float*)d_in[0];
  const float* mask = (const float*)d_in[1];
  const float* Wq = (const float*)d_in[2];
  const float* Wk = (const float*)d_in[3];
  const float* Wv = (const float*)d_in[4];
  float* out = (float*)d_out;
  char* ws = (char*)d_ws;

  u16* Xbf = (u16*)ws;                              // 8 MB
  u16* Wqb = (u16*)(ws + (8u << 20));               // 2 MB
  u16* Wkb = (u16*)(ws + (10u << 20));              // 2 MB
  u16* Wvb = (u16*)(ws + (12u << 20));              // 2 MB
  u16* Qb = (u16*)(ws + (14u << 20));               // 8 MB (BH,S,D)
  u16* Kb = (u16*)(ws + (22u << 20));               // 8 MB (BH,S,D)
  u16* Vtb = (u16*)(ws + (30u << 20));              // 8 MB (BH,D,S)
  float* cos_t = (float*)(ws + (38u << 20));        // 256 KB
  float* sin_t = (float*)(ws + (38u << 20) + (256u << 10));
  float* mask2 = (float*)(ws + (38u << 20) + (512u << 10));  // 16 KB

  prep_kernel<<<7440, 256, 0, stream>>>(hid, Wq, Wk, Wv, mask, Xbf, Wqb, Wkb, Wvb,
                                        cos_t, sin_t, mask2);
  qkv_gemm_kernel<<<dim3(24, 32), 256, 0, stream>>>(Xbf, Wqb, Wkb, Wvb, cos_t, sin_t,
                                                    Qb, Kb, Vtb);
  flash_kernel<<<dim3(16, 32), 256, 0, stream>>>(Qb, Kb, Vtb, mask2, out);
}